// Round 13
// baseline (100.934 us; speedup 1.0000x reference)
//
#include <hip/hip_runtime.h>
#include <hip/hip_bf16.h>
#include <stdint.h>

#define BATCH 32
#define CIN   256
#define COUT  256
#define HW    3136   // 56*56
#define NPAD  3200   // y row stride (pad to 128)

#define AS1 __attribute__((address_space(1)))
#define AS3 __attribute__((address_space(3)))

typedef short bf16x8 __attribute__((ext_vector_type(8)));
typedef float f32x4  __attribute__((ext_vector_type(4)));

__device__ __forceinline__ unsigned short f2bf(float f) {
    unsigned u = __float_as_uint(f);
    u += 0x7fffu + ((u >> 16) & 1u);   // round-to-nearest-even
    return (unsigned short)(u >> 16);
}

// ---------------- K0: fold BN2 into pw weights -----------------------------
__global__ __launch_bounds__(256) void prep_kernel(
        const float* __restrict__ pw_w, const float* __restrict__ pw_b,
        const float* __restrict__ g2, const float* __restrict__ be2,
        const float* __restrict__ mu2, const float* __restrict__ va2,
        unsigned short* __restrict__ Wp, float* __restrict__ b2) {
    int o = blockIdx.x;
    int t = threadIdx.x;
    float inv2 = g2[o] * rsqrtf(va2[o] + 1e-5f);
    Wp[o * CIN + t] = f2bf(pw_w[o * CIN + t] * inv2);
    if (t == 0) b2[o] = pw_b[o] * inv2 + be2[o] - mu2[o] * inv2;
}

// ---------------- K1: depthwise 3x3 + BN1 + ReLU + SELF-CUT -> y bf16 -----
// (frozen since R8)
__global__ __launch_bounds__(256) void dw_kernel(
        const float* __restrict__ x, const float* __restrict__ dww,
        const float* __restrict__ dwb,
        const float* __restrict__ g1, const float* __restrict__ be1,
        const float* __restrict__ mu1, const float* __restrict__ va1,
        unsigned short* __restrict__ y) {
    __shared__ float xs[4 * 3136];
    int tid  = threadIdx.x;
    int lane = tid & 63, wid = tid >> 6;
    int plane = blockIdx.x * 4 + wid;
    int c = plane & 255;

    const float* xp = x + (size_t)plane * HW;
    float* xw = xs + wid * 3136;

#pragma unroll
    for (int i = 0; i < 12; ++i)
        __builtin_amdgcn_global_load_lds(
            (const AS1 void*)(xp + i * 256 + lane * 4),
            (AS3 void*)(xw + i * 256), 16, 0, 0);
    __builtin_amdgcn_global_load_lds(
        (const AS1 void*)(xp + 3072 + lane),
        (AS3 void*)(xw + 3072), 4, 0, 0);

    float w00 = dww[c*9+0], w01 = dww[c*9+1], w02 = dww[c*9+2];
    float w10 = dww[c*9+3], w11 = dww[c*9+4], w12 = dww[c*9+5];
    float w20 = dww[c*9+6], w21 = dww[c*9+7], w22 = dww[c*9+8];
    float inv = g1[c] * rsqrtf(va1[c] + 1e-5f);
    float b0  = dwb[c] * inv + (be1[c] - mu1[c] * inv);

    int  col    = lane < 56 ? lane : 55;
    bool active = lane < 56;
    if (lane == 0)  { w00 = 0.f; w10 = 0.f; w20 = 0.f; }
    if (lane >= 55) { w02 = 0.f; w12 = 0.f; w22 = 0.f; }
    int il = (lane == 0) ? 0 : col - 1;
    int ir = (col == 55) ? 55 : col + 1;

    asm volatile("s_waitcnt vmcnt(0)" ::: "memory");
    __builtin_amdgcn_sched_barrier(0);

    const float* xb = xw;
    unsigned short* yp = y + (size_t)plane * NPAD + col;

    float A = 0.f;
    float Bv = 0.f;
    float lmax = 0.f;
#pragma unroll
    for (int q = 0; q < 56; q += 2) {
        float l0 = xb[q*56 + il],      c0 = xb[q*56 + col],      r0 = xb[q*56 + ir];
        float l1 = xb[(q+1)*56 + il],  c1 = xb[(q+1)*56 + col],  r1 = xb[(q+1)*56 + ir];
        if (q > 0) {
            float o0 = fmaf(l0, w20, fmaf(c0, w21, fmaf(r0, w22, A)));
            float v = fmaxf(fmaf(o0, inv, b0), 0.f);
            if (active) { lmax = fmaxf(lmax, v); yp[(q-1)*56] = f2bf(v); }
        }
        {
            float o1 = fmaf(l0, w10, fmaf(c0, w11, fmaf(r0, w12,
                       fmaf(l1, w20, fmaf(c1, w21, fmaf(r1, w22, Bv))))));
            float v = fmaxf(fmaf(o1, inv, b0), 0.f);
            if (active) { lmax = fmaxf(lmax, v); yp[q*56] = f2bf(v); }
        }
        float top0 = fmaf(l0, w00, fmaf(c0, w01, r0 * w02));
        A  = fmaf(l1, w10, fmaf(c1, w11, fmaf(r1, w12, top0)));
        Bv = fmaf(l1, w00, fmaf(c1, w01, r1 * w02));
    }
    {
        float v = fmaxf(fmaf(A, inv, b0), 0.f);
        if (active) { lmax = fmaxf(lmax, v); yp[55*56] = f2bf(v); }
    }
    for (int off = 32; off >= 1; off >>= 1)
        lmax = fmaxf(lmax, __shfl_xor(lmax, off, 64));
    if (lane < 8) *(uint4*)(y + (size_t)plane * NPAD + HW + lane * 8)
        = make_uint4(0, 0, 0, 0);
    if (lmax < 4.0f) {
        asm volatile("s_waitcnt vmcnt(0)" ::: "memory");
        unsigned short* yp0 = y + (size_t)plane * NPAD;
#pragma unroll
        for (int it = 0; it < 7; ++it) {
            int idx = it * 64 + lane;
            if (idx < 392) *(uint4*)(yp0 + idx * 8) = make_uint4(0, 0, 0, 0);
        }
    }
}

// ---------------- K2: wave-independent pointwise GEMM ----------------------
// Block = (b, nt: 64-col window), 4 waves = 4 o-tiles of 64. NO barriers,
// NO shared LDS: A-frags straight from global (Wp is fragment-ordered,
// L2-resident); B reg-loaded + pack-transposed into wave-private LDS
// (2 x 4KB double-buffer). 2-step lookahead, counted vmcnt(12).
__global__ __launch_bounds__(256, 3) void pw_kernel(
        const unsigned short* __restrict__ y, const unsigned short* __restrict__ Wp,
        const float* __restrict__ b2, float* __restrict__ z,
        float* __restrict__ pwpart) {
    __shared__ __align__(16) char lds[32768];
    int tid = threadIdx.x;
    int lane = tid & 63, wid = tid >> 6;
    char* B0 = lds + wid * 8192;
    char* B1 = B0 + 4096;

    int bid0 = blockIdx.x;                       // 1568 = 8 * 196
    int bid  = (bid0 & 7) * 196 + (bid0 >> 3);   // XCD swizzle (bijective)
    int b  = bid / 49;
    int nt = bid - b * 49;
    int n0 = nt * 64;
    int o0 = wid * 64;                           // wave-owned o-range

    int l15 = lane & 15, l4 = lane >> 4;

    // B geometry: lane = (k4:2b)(nq:4b): rows k4*8..+8, cols nq*4..+4
    int k4 = lane >> 4, nq = lane & 15;
    const unsigned short* bsrc = y + (size_t)b * CIN * NPAD
                               + (size_t)(k4 * 8) * NPAD + n0 + nq * 4;
    // pack dest slots (chunk = k4, halves at +0/+8)
    int sbA[4], sbB[4];
#pragma unroll
    for (int i2 = 0; i2 < 4; ++i2) {
        int nloc = nq * 4 + i2;
        sbA[i2] = nloc * 64 + ((k4 ^ ((nloc >> 2) & 3)) << 4);
        sbB[i2] = sbA[i2] + 8;
    }
    // A fragment source: lane l15 -> o-row, l4 -> k-octet
    const unsigned short* asrcA = Wp + (size_t)(o0 + l15) * CIN + l4 * 8;

    uint2 pr0[8], pr1[8];
    bf16x8 afA[4], afB[4];

#define LOADB(dst, s) { _Pragma("unroll") for (int r = 0; r < 8; ++r)        \
    dst[r] = *(const uint2*)(bsrc + (size_t)((s) * 32 + r) * NPAD); }
#define LOADA(dst, s) { _Pragma("unroll") for (int mf = 0; mf < 4; ++mf)     \
    dst[mf] = *(const bf16x8*)(asrcA + mf * 16 * CIN + (s) * 32); }
#define PIN  __builtin_amdgcn_sched_barrier(0);
#define VM12 { asm volatile("s_waitcnt vmcnt(12)" ::: "memory"); PIN }
#define VM0  { asm volatile("s_waitcnt vmcnt(0)"  ::: "memory"); PIN }
#define LG   { asm volatile("s_waitcnt lgkmcnt(0)" ::: "memory"); PIN }

#define PACK4(src, q, dst, sb_) {                                            \
    uint2 r0 = src[0], r1 = src[1], r2 = src[2], r3 = src[3];                \
    _Pragma("unroll") for (int i2 = 0; i2 < 4; ++i2) {                       \
        unsigned x0 = (i2 & 2) ? r0.y : r0.x;                                \
        unsigned x1 = (i2 & 2) ? r1.y : r1.x;                                \
        unsigned x2 = (i2 & 2) ? r2.y : r2.x;                                \
        unsigned x3 = (i2 & 2) ? r3.y : r3.x;                                \
        if (i2 & 1) { x0 >>= 16; x2 >>= 16; }                                \
        else        { x0 &= 0xffffu; x2 &= 0xffffu; }                        \
        unsigned px = (i2 & 1) ? (x0 | (x1 & 0xffff0000u)) : (x0 | (x1 << 16)); \
        unsigned py = (i2 & 1) ? (x2 | (x3 & 0xffff0000u)) : (x2 | (x3 << 16)); \
        *(uint2*)((dst) + (sb_)[i2]) = make_uint2(px, py);                   \
    } }
#define PACK8(pr, dst) { PACK4(pr, 0, dst, sbA); PACK4((pr + 4), 1, dst, sbB); }

    f32x4 acc[4][4];
#pragma unroll
    for (int mf = 0; mf < 4; ++mf)
#pragma unroll
        for (int nf = 0; nf < 4; ++nf) acc[mf][nf] = {0.f, 0.f, 0.f, 0.f};

#define STEPC(AF, BUF) {                                                     \
    bf16x8 bfr[4];                                                           \
    _Pragma("unroll") for (int nf = 0; nf < 4; ++nf) {                       \
        int n = nf * 16 + l15;                                               \
        bfr[nf] = *(const bf16x8*)((BUF) + n * 64 + ((l4 ^ ((n >> 2) & 3)) << 4)); } \
    _Pragma("unroll") for (int mf = 0; mf < 4; ++mf)                         \
        _Pragma("unroll") for (int nf = 0; nf < 4; ++nf)                     \
            acc[mf][nf] = __builtin_amdgcn_mfma_f32_16x16x32_bf16(           \
                AF[mf], bfr[nf], acc[mf][nf], 0, 0, 0); }

    // ---- pipeline: 2-step lookahead, no barriers ----
    LOADA(afA, 0); LOADB(pr0, 0); PIN;
    LOADA(afB, 1); LOADB(pr1, 1); PIN;
    VM12; PACK8(pr0, B0); LG;

    STEPC(afA, B0);
    LOADA(afA, 2); LOADB(pr0, 2); PIN;
    VM12; PACK8(pr1, B1); LG;

    STEPC(afB, B1);
    LOADA(afB, 3); LOADB(pr1, 3); PIN;
    VM12; PACK8(pr0, B0); LG;

    STEPC(afA, B0);
    LOADA(afA, 4); LOADB(pr0, 4); PIN;
    VM12; PACK8(pr1, B1); LG;

    STEPC(afB, B1);
    LOADA(afB, 5); LOADB(pr1, 5); PIN;
    VM12; PACK8(pr0, B0); LG;

    STEPC(afA, B0);
    LOADA(afA, 6); LOADB(pr0, 6); PIN;
    VM12; PACK8(pr1, B1); LG;

    STEPC(afB, B1);
    LOADA(afB, 7); LOADB(pr1, 7); PIN;
    VM12; PACK8(pr0, B0); LG;

    STEPC(afA, B0);
    VM0; PACK8(pr1, B1); LG;

    STEPC(afB, B1);

#undef LOADB
#undef LOADA
#undef PACK4
#undef PACK8
#undef STEPC

    // ---- epilogue: bias + relu + store + per-(b,o,nt) partial max --------
    float* zb = z + (size_t)b * COUT * HW;
#pragma unroll
    for (int mf = 0; mf < 4; ++mf) {
        int obase = o0 + mf * 16 + l4 * 4;
        float bb0 = b2[obase + 0], bb1 = b2[obase + 1];
        float bb2v = b2[obase + 2], bb3 = b2[obase + 3];
        float rmax[4] = {0.f, 0.f, 0.f, 0.f};
#pragma unroll
        for (int nf = 0; nf < 4; ++nf) {
            int n = n0 + nf * 16 + l15;
            float v0 = fmaxf(acc[mf][nf][0] + bb0, 0.f);
            float v1 = fmaxf(acc[mf][nf][1] + bb1, 0.f);
            float v2 = fmaxf(acc[mf][nf][2] + bb2v, 0.f);
            float v3 = fmaxf(acc[mf][nf][3] + bb3, 0.f);
            zb[(size_t)(obase + 0) * HW + n] = v0;
            zb[(size_t)(obase + 1) * HW + n] = v1;
            zb[(size_t)(obase + 2) * HW + n] = v2;
            zb[(size_t)(obase + 3) * HW + n] = v3;
            rmax[0] = fmaxf(rmax[0], v0);
            rmax[1] = fmaxf(rmax[1], v1);
            rmax[2] = fmaxf(rmax[2], v2);
            rmax[3] = fmaxf(rmax[3], v3);
        }
#pragma unroll
        for (int r = 0; r < 4; ++r) {
            float v = rmax[r];
            v = fmaxf(v, __shfl_xor(v, 1, 64));
            v = fmaxf(v, __shfl_xor(v, 2, 64));
            v = fmaxf(v, __shfl_xor(v, 4, 64));
            v = fmaxf(v, __shfl_xor(v, 8, 64));
            if (l15 == 0)   // plain store: slot unique to this wave
                pwpart[(size_t)(b * COUT + obase + r) * 49 + nt] = v;
        }
    }
}

// ---------------- K3: reduce partial maxes + apply pointwise cut -----------
__global__ __launch_bounds__(256) void cut_kernel(const float* __restrict__ pwpart,
                                                  float* __restrict__ z) {
    int plane = blockIdx.x * 8 + (threadIdx.x >> 5);   // 8192 planes
    int l = threadIdx.x & 31;
    float m = 0.f;
    for (int i = l; i < 49; i += 32)
        m = fmaxf(m, pwpart[(size_t)plane * 49 + i]);
    for (int off = 16; off >= 1; off >>= 1)
        m = fmaxf(m, __shfl_xor(m, off, 32));
    if (m >= 1e-3f) return;
    float4* zp = (float4*)(z + (size_t)plane * HW);
    for (int i = l; i < HW / 4; i += 32)
        zp[i] = make_float4(0.f, 0.f, 0.f, 0.f);
}

extern "C" void kernel_launch(void* const* d_in, const int* in_sizes, int n_in,
                              void* d_out, int out_size, void* d_ws, size_t ws_size,
                              hipStream_t stream) {
    const float* x   = (const float*)d_in[0];
    const float* dww = (const float*)d_in[1];
    const float* dwb = (const float*)d_in[2];
    const float* g1  = (const float*)d_in[3];
    const float* be1 = (const float*)d_in[4];
    const float* mu1 = (const float*)d_in[5];
    const float* va1 = (const float*)d_in[6];
    const float* pww = (const float*)d_in[7];
    const float* pwb = (const float*)d_in[8];
    const float* g2  = (const float*)d_in[9];
    const float* be2 = (const float*)d_in[10];
    const float* mu2 = (const float*)d_in[11];
    const float* va2 = (const float*)d_in[12];
    float* z = (float*)d_out;

    char* ws = (char*)d_ws;
    const size_t Y_BYTES = (size_t)BATCH * CIN * NPAD * 2;  // 52,428,800
    unsigned short* y  = (unsigned short*)ws;
    unsigned short* Wp = (unsigned short*)(ws + Y_BYTES);
    float* b2          = (float*)(ws + Y_BYTES + 131072);
    float* pwpart      = (float*)(ws + Y_BYTES + 131072 + 1024);  // 8192*49*4B

    prep_kernel<<<256, 256, 0, stream>>>(pww, pwb, g2, be2, mu2, va2, Wp, b2);
    dw_kernel<<<2048, 256, 0, stream>>>(x, dww, dwb, g1, be1, mu1, va1, y);
    pw_kernel<<<BATCH * 49, 256, 0, stream>>>(y, Wp, b2, z, pwpart);
    cut_kernel<<<BATCH * COUT / 8, 256, 0, stream>>>(pwpart, z);
}